// Round 3
// baseline (304.257 us; speedup 1.0000x reference)
//
#include <hip/hip_runtime.h>

typedef _Float16 f16;
typedef _Float16 f16x4 __attribute__((ext_vector_type(4)));
typedef _Float16 f16x8 __attribute__((ext_vector_type(8)));
typedef float f32x4 __attribute__((ext_vector_type(4)));
typedef float f32x16 __attribute__((ext_vector_type(16)));
typedef unsigned u32x4 __attribute__((ext_vector_type(4)));

#define DEVINL __device__ __forceinline__
#define VMCNT(n) asm volatile("s_waitcnt vmcnt(" #n ")" ::: "memory")

// async global->LDS, 16B per lane. LDS dest must be uniform-base + lane*16.
DEVINL void gload16(const void* g, void* l) {
    __builtin_amdgcn_global_load_lds(
        (const __attribute__((address_space(1))) unsigned int*)g,
        (__attribute__((address_space(3))) unsigned int*)l, 16, 0, 0);
}

DEVINL unsigned pk2(float a, float b) {
    auto v = __builtin_amdgcn_cvt_pkrtz(a, b);  // v_cvt_pkrtz_f16_f32
    return __builtin_bit_cast(unsigned, v);
}

// ---------------------------------------------------------------- convert
__global__ __launch_bounds__(256) void cvt_kernel(const float* __restrict__ in,
                                                  f16* __restrict__ out, int n4) {
    int i = blockIdx.x * 256 + threadIdx.x;
    int st = gridDim.x * 256;
    for (; i < n4; i += st) {
        float4 v = reinterpret_cast<const float4*>(in)[i];
        f16x4 o = {(f16)v.x, (f16)v.y, (f16)v.z, (f16)v.w};
        reinterpret_cast<f16x4*>(out)[i] = o;
    }
}

// ---------------------------------------------------------------- in_proj GEMM (ring-4, counted vmcnt)
// C[M=8192, N=3072] = A[M,1024] * B[N,1024]^T + bias, fp16 in, scatter epilogue.
// Tile 128x384, BK=32, 512 thr = 8 waves (2M x 4N), wave tile 64x96 (acc[4][6]).
// LDS: ring of 4 K-tiles (As 8KB + Bs 24KB each) = 128 KB. Prefetch depth 3,
// raw s_barrier + vmcnt(8) steady (never drains). Swizzle ((row>>1)&3)<<4 on
// 64-B rows, pre-swizzled global source (both-sides rule).
// Epilogue: Q (prescaled by 0.125*log2e), K -> [b,h,s,d]; V -> [b,h,d,s].
__global__ __launch_bounds__(512) void gemm_in(const f16* __restrict__ A,
                                               const f16* __restrict__ Bm,
                                               const float* __restrict__ bias,
                                               f16* __restrict__ Qw, f16* __restrict__ Kw,
                                               f16* __restrict__ Vtw) {
    constexpr int NKT = 32;  // K=1024 / BK=32
    __shared__ f16 As[4][128 * 32];
    __shared__ f16 Bs[4][384 * 32];
    const int t = threadIdx.x;
    const int w = t >> 6, lane = t & 63, lr = lane & 15, lg = lane >> 4;
    const int wm = w >> 2, wn = w & 3;
    const int m0 = blockIdx.y * 128, n0 = blockIdx.x * 384;

    // staging source pointers (pre-swizzled)
    const int srow = t >> 2, scol = (t & 3) * 16;
    const char* Asrc = (const char*)(A + (m0 + srow) * 1024) + (scol ^ (((srow >> 1) & 3) << 4));
    const char* Bsrc[3];
#pragma unroll
    for (int r = 0; r < 3; ++r) {
        int row = r * 128 + srow;
        Bsrc[r] = (const char*)(Bm + (n0 + row) * 1024) + (scol ^ (((row >> 1) & 3) << 4));
    }

    auto stage = [&](int buf, int kt) {
        gload16(Asrc + kt * 64, (char*)&As[buf][0] + t * 16);
#pragma unroll
        for (int r = 0; r < 3; ++r)
            gload16(Bsrc[r] + kt * 64, (char*)&Bs[buf][0] + r * 8192 + t * 16);
    };

    // fragment LDS byte offsets (loop-invariant)
    int offA[4], offB[6];
#pragma unroll
    for (int mf = 0; mf < 4; ++mf) {
        int row = wm * 64 + mf * 16 + lr;
        offA[mf] = row * 64 + ((lg * 16) ^ (((row >> 1) & 3) << 4));
    }
#pragma unroll
    for (int nf = 0; nf < 6; ++nf) {
        int row = wn * 96 + nf * 16 + lr;
        offB[nf] = row * 64 + ((lg * 16) ^ (((row >> 1) & 3) << 4));
    }

    f32x4 acc[4][6] = {};

    stage(0, 0);
    stage(1, 1);
    stage(2, 2);
    VMCNT(8);  // own slice of kt=0 landed

    for (int kt = 0; kt < NKT; ++kt) {
        __builtin_amdgcn_s_barrier();
        if (kt + 3 < NKT) stage((kt + 3) & 3, kt + 3);
        const char* ab = (const char*)&As[kt & 3][0];
        const char* bb = (const char*)&Bs[kt & 3][0];
        f16x8 af[4], bf[6];
#pragma unroll
        for (int mf = 0; mf < 4; ++mf) af[mf] = *(const f16x8*)(ab + offA[mf]);
#pragma unroll
        for (int nf = 0; nf < 6; ++nf) bf[nf] = *(const f16x8*)(bb + offB[nf]);
        __builtin_amdgcn_s_setprio(1);
#pragma unroll
        for (int mf = 0; mf < 4; ++mf)
#pragma unroll
            for (int nf = 0; nf < 6; ++nf)
                acc[mf][nf] = __builtin_amdgcn_mfma_f32_16x16x32_f16(af[mf], bf[nf], acc[mf][nf], 0, 0, 0);
        __builtin_amdgcn_s_setprio(0);
        // pre-barrier wait: own slice of kt+1 landed (counted, never drains in steady state)
        if (kt <= NKT - 4) VMCNT(8);
        else if (kt == NKT - 3) VMCNT(4);
        else if (kt == NKT - 2) VMCNT(0);
    }

    // epilogue: scatter Q (prescaled), K, Vt with bias
    const float SCQ = 0.18033688011112042f;  // (1/sqrt(64)) * log2(e)
#pragma unroll
    for (int nf = 0; nf < 6; ++nf) {
        int n = n0 + wn * 96 + nf * 16 + lr;
        float bv = bias[n];
        int part = n >> 10, e = n & 1023, hh = e >> 6, dd = e & 63;
#pragma unroll
        for (int mf = 0; mf < 4; ++mf) {
            int m = m0 + wm * 64 + mf * 16 + lg * 4;
            int bb2 = m >> 10, ss = m & 1023;
            if (part == 0) {
                f16* dst = Qw + ((bb2 * 16 + hh) * 1024 + ss) * 64 + dd;
#pragma unroll
                for (int r = 0; r < 4; ++r) dst[r * 64] = (f16)((acc[mf][nf][r] + bv) * SCQ);
            } else if (part == 1) {
                f16* dst = Kw + ((bb2 * 16 + hh) * 1024 + ss) * 64 + dd;
#pragma unroll
                for (int r = 0; r < 4; ++r) dst[r * 64] = (f16)(acc[mf][nf][r] + bv);
            } else {
                f16x4 pkv;
#pragma unroll
                for (int r = 0; r < 4; ++r) pkv[r] = (f16)(acc[mf][nf][r] + bv);
                *(f16x4*)(Vtw + ((bb2 * 16 + hh) * 64 + dd) * 1024 + ss) = pkv;
            }
        }
    }
}

// ---------------------------------------------------------------- out_proj GEMM (round-1 structure, passed)
__global__ __launch_bounds__(256) void gemm_out(const f16* __restrict__ A,
                                                const f16* __restrict__ Bm,
                                                const float* __restrict__ bias,
                                                float* __restrict__ Cout) {
    constexpr int K = 1024, NT = K / 32;
    __shared__ f16 As[2][128 * 32];
    __shared__ f16 Bs[2][128 * 32];
    const int t = threadIdx.x;
    const int wave = t >> 6, lane = t & 63, lr = lane & 15, lg = lane >> 4;
    const int wr = wave >> 1, wc = wave & 1;
    const int m0 = blockIdx.y * 128, n0 = blockIdx.x * 128;

    const f16* Ag = A + (m0 + (t >> 2)) * K + (t & 3) * 8;
    const f16* Bg = Bm + (n0 + (t >> 2)) * K + (t & 3) * 8;

    f32x4 acc[4][4] = {};

    auto stage = [&](int buf, int kt) {
        const f16* a = Ag + kt * 32;
        const f16* b = Bg + kt * 32;
        f16* al = &As[buf][t * 8];
        f16* bl = &Bs[buf][t * 8];
        gload16(a, al);
        gload16(a + 64 * K, al + 64 * 32);
        gload16(b, bl);
        gload16(b + 64 * K, bl + 64 * 32);
    };

    stage(0, 0);
    __syncthreads();
    int cur = 0;
    for (int kt = 0; kt < NT; ++kt) {
        if (kt + 1 < NT) stage(cur ^ 1, kt + 1);
        const f16* as = &As[cur][0];
        const f16* bs = &Bs[cur][0];
        f16x8 af[4], bf[4];
#pragma unroll
        for (int i = 0; i < 4; ++i)
            af[i] = *(const f16x8*)&as[(wr * 64 + i * 16 + lr) * 32 + lg * 8];
#pragma unroll
        for (int i = 0; i < 4; ++i)
            bf[i] = *(const f16x8*)&bs[(wc * 64 + i * 16 + lr) * 32 + lg * 8];
#pragma unroll
        for (int i = 0; i < 4; ++i)
#pragma unroll
            for (int j = 0; j < 4; ++j)
                acc[i][j] = __builtin_amdgcn_mfma_f32_16x16x32_f16(af[i], bf[j], acc[i][j], 0, 0, 0);
        __syncthreads();
        cur ^= 1;
    }
#pragma unroll
    for (int nf = 0; nf < 4; ++nf) {
        int n = n0 + wc * 64 + nf * 16 + lr;
        float bv = bias[n];
#pragma unroll
        for (int mf = 0; mf < 4; ++mf) {
            int m = m0 + wr * 64 + mf * 16 + lg * 4;
#pragma unroll
            for (int r = 0; r < 4; ++r) Cout[(m + r) * 1024 + n] = acc[mf][nf][r] + bv;
        }
    }
}

// ---------------------------------------------------------------- flash attention (ring-4, defer-max)
// grid (8 qtiles, 16 heads, 8 batch), 256 thr = 4 waves x 32 q-rows.
// Q is PRESCALED by 0.125*log2e in gemm_in. Ring of 4 K/V slots (64 KB LDS),
// prefetch depth 3, raw barriers + counted vmcnt (never drains mid-loop).
__global__ __launch_bounds__(256) void attn_kernel(const f16* __restrict__ Qw,
                                                   const f16* __restrict__ Kw,
                                                   const f16* __restrict__ Vtw,
                                                   f16* __restrict__ AO) {
    __shared__ f16 Ksm[4][64 * 64];
    __shared__ f16 Vsm[4][64 * 64];
    const int t = threadIdx.x, wave = t >> 6, lane = t & 63;
    const int ql = lane & 31, hi = lane >> 5;
    const int b = blockIdx.z, h = blockIdx.y, qt = blockIdx.x;
    const f16* Qp = Qw + (b * 16 + h) * 1024 * 64;
    const f16* Kp = Kw + (b * 16 + h) * 1024 * 64;
    const f16* Vp = Vtw + (b * 16 + h) * 64 * 1024;
    const int q0 = qt * 128 + wave * 32;

    // Q as B-operand (prescaled): qb[s] = Q[q0+ql][s*16 + hi*8 + j]
    f16x8 qb[4];
#pragma unroll
    for (int s = 0; s < 4; ++s)
        qb[s] = *(const f16x8*)&Qp[(q0 + ql) * 64 + s * 16 + hi * 8];

    // staging: row/gw fixed per thread; per-tile offset = kv*8192 (K) / kv*128 (V) bytes
    const int srow0 = t >> 3;
    const int sw = ((t & 7) << 4);
    auto stage_kv = [&](int slot, int kv) {  // kv = tile index * 64
#pragma unroll
        for (int c = 0; c < 2; ++c) {
            int row = c * 32 + srow0;
            int gw = sw ^ ((row & 7) << 4);
            gload16((const char*)(Kp + (kv + row) * 64) + gw,
                    (char*)&Ksm[slot][0] + c * 4096 + t * 16);
            gload16((const char*)(Vp + row * 1024 + kv) + gw,
                    (char*)&Vsm[slot][0] + c * 4096 + t * 16);
        }
    };

    f32x16 o0 = 0.f, o1 = 0.f;
    float mraw = -1e30f, lsum = 0.f;

    stage_kv(0, 0);
    stage_kv(1, 64);
    stage_kv(2, 128);
    VMCNT(8);  // slot 0 (own slice) landed

    for (int kv = 0; kv < 16; ++kv) {
        __builtin_amdgcn_s_barrier();
        if (kv + 3 < 16) stage_kv((kv + 3) & 3, (kv + 3) * 64);
        const char* Kb = (const char*)&Ksm[kv & 3][0];
        const char* Vb = (const char*)&Vsm[kv & 3][0];

        // ---- QK^T (swapped): st0 = S^T[kk 0..31][q], st1 = S^T[kk 32..63][q]
        f32x16 st0, st1;
        __builtin_amdgcn_s_setprio(1);
#pragma unroll
        for (int s = 0; s < 4; ++s) {
            int r0 = ql, r1 = 32 + ql;
            int byt = (s * 32 + hi * 16) ^ ((r0 & 7) << 4);
            f16x8 k0 = *(const f16x8*)(Kb + r0 * 128 + byt);
            f16x8 k1 = *(const f16x8*)(Kb + r1 * 128 + byt);
            if (s == 0) {
                st0 = __builtin_amdgcn_mfma_f32_32x32x16_f16(k0, qb[0], (f32x16)0.f, 0, 0, 0);
                st1 = __builtin_amdgcn_mfma_f32_32x32x16_f16(k1, qb[0], (f32x16)0.f, 0, 0, 0);
            } else {
                st0 = __builtin_amdgcn_mfma_f32_32x32x16_f16(k0, qb[s], st0, 0, 0, 0);
                st1 = __builtin_amdgcn_mfma_f32_32x32x16_f16(k1, qb[s], st1, 0, 0, 0);
            }
        }
        __builtin_amdgcn_s_setprio(0);

        // ---- lane-local online softmax with defer-max (T13, THR=8 in log2 units)
        float mx = st0[0];
#pragma unroll
        for (int r = 1; r < 16; ++r) mx = fmaxf(mx, st0[r]);
#pragma unroll
        for (int r = 0; r < 16; ++r) mx = fmaxf(mx, st1[r]);
        mx = fmaxf(mx, __shfl_xor(mx, 32, 64));

        if (__all(mx <= mraw + 8.f)) {
            float ps = 0.f;
#pragma unroll
            for (int r = 0; r < 16; ++r) {
                float p = exp2f(st0[r] - mraw);
                st0[r] = p;
                ps += p;
            }
#pragma unroll
            for (int r = 0; r < 16; ++r) {
                float p = exp2f(st1[r] - mraw);
                st1[r] = p;
                ps += p;
            }
            ps += __shfl_xor(ps, 32, 64);
            lsum += ps;
        } else {
            float mn = fmaxf(mraw, mx);
            float al = exp2f(mraw - mn);
            mraw = mn;
            float ps = 0.f;
#pragma unroll
            for (int r = 0; r < 16; ++r) {
                float p = exp2f(st0[r] - mn);
                st0[r] = p;
                ps += p;
            }
#pragma unroll
            for (int r = 0; r < 16; ++r) {
                float p = exp2f(st1[r] - mn);
                st1[r] = p;
                ps += p;
            }
            ps += __shfl_xor(ps, 32, 64);
            lsum = lsum * al + ps;
            o0 *= al;
            o1 *= al;
        }

        // ---- PV (swapped): O^T[d][q] += V^T[d][kk] P^T[kk][q]
#pragma unroll
        for (int s = 0; s < 4; ++s) {
            const int s1 = s & 1;
            float p0, p1, p2, p3, p4, p5, p6, p7;
            if (s < 2) {
                p0 = st0[8 * s1 + 0]; p1 = st0[8 * s1 + 1]; p2 = st0[8 * s1 + 2]; p3 = st0[8 * s1 + 3];
                p4 = st0[8 * s1 + 4]; p5 = st0[8 * s1 + 5]; p6 = st0[8 * s1 + 6]; p7 = st0[8 * s1 + 7];
            } else {
                p0 = st1[8 * s1 + 0]; p1 = st1[8 * s1 + 1]; p2 = st1[8 * s1 + 2]; p3 = st1[8 * s1 + 3];
                p4 = st1[8 * s1 + 4]; p5 = st1[8 * s1 + 5]; p6 = st1[8 * s1 + 6]; p7 = st1[8 * s1 + 7];
            }
            unsigned c0 = pk2(p0, p1), c1 = pk2(p2, p3);
            unsigned c2 = pk2(p4, p5), c3 = pk2(p6, p7);
            unsigned y0 = __shfl_xor(hi ? c0 : c2, 32, 64);
            unsigned y1 = __shfl_xor(hi ? c1 : c3, 32, 64);
            unsigned w0 = hi ? y0 : c0;
            unsigned w1 = hi ? y1 : c1;
            unsigned w2 = hi ? c2 : y0;
            unsigned w3 = hi ? c3 : y1;
            u32x4 pw = {w0, w1, w2, w3};
            f16x8 pf = __builtin_bit_cast(f16x8, pw);
            __builtin_amdgcn_s_setprio(1);
#pragma unroll
            for (int db = 0; db < 2; ++db) {
                int row = db * 32 + ql;
                int byt = (s * 32 + hi * 16) ^ ((row & 7) << 4);
                f16x8 vf = *(const f16x8*)(Vb + row * 128 + byt);
                if (db == 0)
                    o0 = __builtin_amdgcn_mfma_f32_32x32x16_f16(vf, pf, o0, 0, 0, 0);
                else
                    o1 = __builtin_amdgcn_mfma_f32_32x32x16_f16(vf, pf, o1, 0, 0, 0);
            }
            __builtin_amdgcn_s_setprio(0);
        }
        // pre-barrier wait: own slice of kv+1 landed
        if (kv <= 12) VMCNT(8);
        else if (kv == 13) VMCNT(4);
        else if (kv == 14) VMCNT(0);
    }

    // ---- epilogue: O^T -> LDS (swizzled transpose in Ksm slots 0-1) -> coalesced AO
    float inv = 1.0f / lsum;
    char* obase = (char*)&Ksm[0][0] + wave * 4096;
#pragma unroll
    for (int db = 0; db < 2; ++db)
#pragma unroll
        for (int r = 0; r < 16; ++r) {
            int d = db * 32 + (r & 3) + 8 * (r >> 2) + 4 * hi;
            float v = (db == 0 ? o0[r] : o1[r]) * inv;
            *(f16*)(obase + ql * 128 + ((2 * d) ^ ((ql & 7) << 4))) = (f16)v;
        }
    __syncthreads();
    const int rl = lane >> 1, c4 = (lane & 1) * 4;
#pragma unroll
    for (int i = 0; i < 4; ++i) {
        f16x8 ov = *(const f16x8*)(obase + rl * 128 + (((c4 + i) * 16) ^ ((rl & 7) << 4)));
        *(f16x8*)&AO[(b * 1024 + q0 + rl) * 1024 + h * 64 + (c4 + i) * 8] = ov;
    }
}

// ---------------------------------------------------------------- launch
extern "C" void kernel_launch(void* const* d_in, const int* in_sizes, int n_in,
                              void* d_out, int out_size, void* d_ws, size_t ws_size,
                              hipStream_t stream) {
    const float* qkv = (const float*)d_in[0];
    const float* w_in = (const float*)d_in[1];
    const float* b_in = (const float*)d_in[2];
    const float* w_out = (const float*)d_in[3];
    const float* b_out = (const float*)d_in[4];
    float* out = (float*)d_out;

    f16* Xh = (f16*)d_ws;            // 8192*1024
    f16* Wih = Xh + 8388608;         // 3072*1024
    f16* Woh = Wih + 3145728;        // 1024*1024
    f16* Qw = Woh + 1048576;         // [8][16][1024][64]  (prescaled)
    f16* Kw = Qw + 8388608;          // [8][16][1024][64]
    f16* Vtw = Kw + 8388608;         // [8][16][64][1024]
    f16* AO = Xh;

    cvt_kernel<<<2048, 256, 0, stream>>>(qkv, Xh, 8388608 / 4);
    cvt_kernel<<<1024, 256, 0, stream>>>(w_in, Wih, 3145728 / 4);
    cvt_kernel<<<512, 256, 0, stream>>>(w_out, Woh, 1048576 / 4);

    gemm_in<<<dim3(8, 64), 512, 0, stream>>>(Xh, Wih, b_in, Qw, Kw, Vtw);
    attn_kernel<<<dim3(8, 16, 8), 256, 0, stream>>>(Qw, Kw, Vtw, AO);
    gemm_out<<<dim3(8, 64), 256, 0, stream>>>(AO, Woh, b_out, out);
}